// Round 1
// baseline (2775.524 us; speedup 1.0000x reference)
//
#include <hip/hip_runtime.h>
#include <cstdint>
#include <cstddef>

#define NN   50000
#define NE   500000
#define DIN  64
#define EDIM 32
#define NH   4
#define NC   64
#define HC   256   // NH*NC
#define NGG  64
#define ND   64
#define LN_EPS 1e-5f

// ---------------------------------------------------------------------------
// CSR build: degree count -> single-block scan -> fill
// ---------------------------------------------------------------------------
__global__ void count_deg(const int* __restrict__ dst, int* __restrict__ deg) {
    int e = blockIdx.x * blockDim.x + threadIdx.x;
    if (e < NE) atomicAdd(&deg[dst[e]], 1);
}

// cursor holds deg on entry; on exit cursor[n] = row start, row_ptr filled.
__global__ void scan_deg(int* __restrict__ cursor, int* __restrict__ row_ptr) {
    __shared__ int sums[1024];
    const int T = 1024;
    const int chunk = (NN + T - 1) / T;  // 49
    int t = threadIdx.x;
    int lo = t * chunk, hi = min(lo + chunk, NN);
    int s = 0;
    for (int i = lo; i < hi; i++) s += cursor[i];
    sums[t] = s;
    __syncthreads();
    for (int off = 1; off < T; off <<= 1) {   // inclusive Hillis-Steele
        int v = (t >= off) ? sums[t - off] : 0;
        __syncthreads();
        sums[t] += v;
        __syncthreads();
    }
    int base = (t == 0) ? 0 : sums[t - 1];
    for (int i = lo; i < hi; i++) {
        int d = cursor[i];
        row_ptr[i] = base;
        cursor[i] = base;
        base += d;
    }
    if (t == 0) row_ptr[NN] = NE;
}

__global__ void fill_csr(const int* __restrict__ src, const int* __restrict__ dst,
                         int* __restrict__ cursor, int* __restrict__ csr_src,
                         int* __restrict__ csr_eid) {
    int e = blockIdx.x * blockDim.x + threadIdx.x;
    if (e < NE) {
        int d = dst[e];
        int pos = atomicAdd(&cursor[d], 1);
        csr_src[pos] = src[e];
        csr_eid[pos] = e;
    }
}

// loop_attr[n][c] = mean over incident (dst) edges of edge_feature, 0 if deg==0
__global__ void loop_attr_kernel(const float* __restrict__ ef, const int* __restrict__ row_ptr,
                                 const int* __restrict__ csr_eid, float* __restrict__ loop_attr) {
    int idx = blockIdx.x * blockDim.x + threadIdx.x;
    if (idx >= NN * EDIM) return;
    int n = idx >> 5, c = idx & 31;
    int s = row_ptr[n], e = row_ptr[n + 1];
    float acc = 0.f;
    for (int j = s; j < e; j++) acc += ef[(size_t)csr_eid[j] * EDIM + c];
    int d = e - s;
    loop_attr[(size_t)n * EDIM + c] = acc / (float)max(d, 1);
}

// ---------------------------------------------------------------------------
// fp32 GEMM + bias: C[M,Nn] = A[M,K] @ B[K,Nn] + bias.  BM=128 BN=64 BK=16,
// 256 threads, 8x4 microtile. K%16==0, Nn%64==0 assumed.
// ---------------------------------------------------------------------------
__global__ void gemm_bias(const float* __restrict__ A, const float* __restrict__ B,
                          const float* __restrict__ bias, float* __restrict__ Cout,
                          int M, int K, int Nn) {
    __shared__ __align__(16) float As[16][132];  // [k][row], padded (132%32=4 -> 2-way on store)
    __shared__ __align__(16) float Bs[16][64];   // [k][col]
    int tid = threadIdx.x;
    int tx = tid & 15;        // col group (4 cols)
    int ty = tid >> 4;        // row group (8 rows)
    int rowBase = blockIdx.y * 128;
    int colBase = blockIdx.x * 64;
    float acc[8][4] = {};
    for (int kk = 0; kk < K; kk += 16) {
        #pragma unroll
        for (int t = 0; t < 2; t++) {            // A tile: 128x16 = 512 float4
            int f = tid + 256 * t;
            int r = f >> 2;                      // 0..127
            int k4 = (f & 3) * 4;
            float4 v = make_float4(0.f, 0.f, 0.f, 0.f);
            int row = rowBase + r;
            if (row < M) v = *(const float4*)(A + (size_t)row * K + kk + k4);
            As[k4 + 0][r] = v.x; As[k4 + 1][r] = v.y;
            As[k4 + 2][r] = v.z; As[k4 + 3][r] = v.w;
        }
        {                                        // B tile: 16x64
            int k = tid >> 4;
            int c4 = (tid & 15) * 4;
            *(float4*)&Bs[k][c4] = *(const float4*)(B + (size_t)(kk + k) * Nn + colBase + c4);
        }
        __syncthreads();
        #pragma unroll
        for (int k = 0; k < 16; k++) {
            float4 a0 = *(const float4*)&As[k][ty * 8];
            float4 a1 = *(const float4*)&As[k][ty * 8 + 4];
            float4 b4 = *(const float4*)&Bs[k][tx * 4];
            float av[8] = {a0.x, a0.y, a0.z, a0.w, a1.x, a1.y, a1.z, a1.w};
            float bv[4] = {b4.x, b4.y, b4.z, b4.w};
            #pragma unroll
            for (int i = 0; i < 8; i++)
                #pragma unroll
                for (int j = 0; j < 4; j++)
                    acc[i][j] += av[i] * bv[j];
        }
        __syncthreads();
    }
    float4 bb = *(const float4*)(bias + colBase + tx * 4);
    #pragma unroll
    for (int i = 0; i < 8; i++) {
        int row = rowBase + ty * 8 + i;
        if (row < M) {
            float4 r = make_float4(acc[i][0] + bb.x, acc[i][1] + bb.y,
                                   acc[i][2] + bb.z, acc[i][3] + bb.w);
            *(float4*)(Cout + (size_t)row * Nn + colBase + tx * 4) = r;
        }
    }
}

// ---------------------------------------------------------------------------
// alpha[e,h] = sum_c leaky(xl[src,h,c]+xr[dst,h,c]+ (ea@We)[h,c]) * att[h,c]
// One wave per item; items 0..NE-1 are edges, NE..NE+NN-1 are self-loops.
// We is held in 128 VGPRs/lane; ea read via wave-uniform (scalar) loads.
// lane holds hc = 4*lane..4*lane+3  (head h = lane>>4, c = 4*(lane&15)+i).
// ---------------------------------------------------------------------------
__global__ void alpha_kernel(const int* __restrict__ srcA, const int* __restrict__ dstA,
                             const float* __restrict__ ef, const float* __restrict__ loop_attr,
                             const float* __restrict__ xl, const float* __restrict__ xr,
                             const float* __restrict__ We, const float* __restrict__ att,
                             float* __restrict__ alpha) {
    int lane = threadIdx.x & 63;
    int wv = threadIdx.x >> 6;
    int wave = blockIdx.x * 4 + wv;
    int nwaves = gridDim.x * 4;
    float4 wreg[32];
    #pragma unroll
    for (int k = 0; k < 32; k++)
        wreg[k] = *(const float4*)(We + k * HC + 4 * lane);
    int h = lane >> 4;
    float4 attv = *(const float4*)(att + h * NC + 4 * (lane & 15));
    const int IT = NE + NN;
    for (int it0 = wave; it0 < IT; it0 += nwaves) {
        int it = __builtin_amdgcn_readfirstlane(it0);
        int s, d;
        const float* eap;
        if (it < NE) {
            s = __builtin_amdgcn_readfirstlane(srcA[it]);
            d = __builtin_amdgcn_readfirstlane(dstA[it]);
            eap = ef + (size_t)it * EDIM;
        } else {
            s = it - NE; d = s;
            eap = loop_attr + (size_t)s * EDIM;
        }
        float ea[32];
        #pragma unroll
        for (int q = 0; q < 8; q++) {
            float4 t = *(const float4*)(eap + 4 * q);
            ea[4 * q] = t.x; ea[4 * q + 1] = t.y; ea[4 * q + 2] = t.z; ea[4 * q + 3] = t.w;
        }
        float4 ee = make_float4(0.f, 0.f, 0.f, 0.f);
        #pragma unroll
        for (int k = 0; k < 32; k++) {
            ee.x += ea[k] * wreg[k].x;
            ee.y += ea[k] * wreg[k].y;
            ee.z += ea[k] * wreg[k].z;
            ee.w += ea[k] * wreg[k].w;
        }
        float4 xlv = *(const float4*)(xl + (size_t)s * HC + 4 * lane);
        float4 xrv = *(const float4*)(xr + (size_t)d * HC + 4 * lane);
        float m0 = xlv.x + xrv.x + ee.x; m0 = m0 > 0.f ? m0 : 0.2f * m0;
        float m1 = xlv.y + xrv.y + ee.y; m1 = m1 > 0.f ? m1 : 0.2f * m1;
        float m2 = xlv.z + xrv.z + ee.z; m2 = m2 > 0.f ? m2 : 0.2f * m2;
        float m3 = xlv.w + xrv.w + ee.w; m3 = m3 > 0.f ? m3 : 0.2f * m3;
        float p = m0 * attv.x + m1 * attv.y + m2 * attv.z + m3 * attv.w;
        p += __shfl_xor(p, 1);
        p += __shfl_xor(p, 2);
        p += __shfl_xor(p, 4);
        p += __shfl_xor(p, 8);
        if ((lane & 15) == 0) alpha[(size_t)it * NH + h] = p;
    }
}

// ---------------------------------------------------------------------------
// Per-node softmax + weighted aggregation over CSR. One wave per node.
// out[n,hc] = (sum_e xl[src_e,hc]*exp(alpha_e - mx)) / denom + bias[hc]
// ---------------------------------------------------------------------------
__global__ void aggregate_kernel(const float* __restrict__ xl, const float* __restrict__ alpha,
                                 const int* __restrict__ row_ptr, const int* __restrict__ csr_src,
                                 const int* __restrict__ csr_eid, const float* __restrict__ bias,
                                 float* __restrict__ out, int do_relu) {
    int lane = threadIdx.x & 63;
    int wv = threadIdx.x >> 6;
    int n = blockIdx.x * 4 + wv;
    if (n >= NN) return;
    n = __builtin_amdgcn_readfirstlane(n);
    int h = lane >> 4;
    int s0 = row_ptr[n], e0 = row_ptr[n + 1];
    float aself = alpha[(size_t)(NE + n) * NH + h];
    float mx = aself;
    for (int j = s0; j < e0; j++) {
        int eid = csr_eid[j];
        mx = fmaxf(mx, alpha[(size_t)eid * NH + h]);
    }
    float a = __expf(aself - mx);
    float denom = a;
    float4 xv = *(const float4*)(xl + (size_t)n * HC + 4 * lane);
    float4 acc = make_float4(xv.x * a, xv.y * a, xv.z * a, xv.w * a);
    for (int j = s0; j < e0; j++) {
        int eid = csr_eid[j];
        int sn = csr_src[j];
        float aa = __expf(alpha[(size_t)eid * NH + h] - mx);
        denom += aa;
        float4 x4 = *(const float4*)(xl + (size_t)sn * HC + 4 * lane);
        acc.x += x4.x * aa; acc.y += x4.y * aa;
        acc.z += x4.z * aa; acc.w += x4.w * aa;
    }
    float inv = 1.f / denom;
    float4 bb = *(const float4*)(bias + 4 * lane);
    float4 r = make_float4(acc.x * inv + bb.x, acc.y * inv + bb.y,
                           acc.z * inv + bb.z, acc.w * inv + bb.w);
    if (do_relu) {
        r.x = fmaxf(r.x, 0.f); r.y = fmaxf(r.y, 0.f);
        r.z = fmaxf(r.z, 0.f); r.w = fmaxf(r.w, 0.f);
    }
    *(float4*)(out + (size_t)n * HC + 4 * lane) = r;
}

// ---------------------------------------------------------------------------
// In-place LayerNorm over rows of width 64 (one wave per row)
// ---------------------------------------------------------------------------
__global__ void ln_rows(float* __restrict__ y, const float* __restrict__ g,
                        const float* __restrict__ b, int M) {
    int lane = threadIdx.x & 63;
    int wv = threadIdx.x >> 6;
    int n = blockIdx.x * 4 + wv;
    if (n >= M) return;
    float v = y[(size_t)n * 64 + lane];
    float s = v;
    #pragma unroll
    for (int o = 32; o >= 1; o >>= 1) s += __shfl_xor(s, o);
    float mu = s * (1.f / 64.f);
    float dv = v - mu;
    float q = dv * dv;
    #pragma unroll
    for (int o = 32; o >= 1; o >>= 1) q += __shfl_xor(q, o);
    float var = q * (1.f / 64.f);
    y[(size_t)n * 64 + lane] = dv * rsqrtf(var + LN_EPS) * g[lane] + b[lane];
}

// ---------------------------------------------------------------------------
// Graph mean pre-reduction exploiting sorted batch: one block per 256 rows,
// thread = column; flush partial sum on graph change (few atomics).
// ---------------------------------------------------------------------------
__global__ void graph_sum(const float* __restrict__ x, const int* __restrict__ batch,
                          float* __restrict__ gsum, float* __restrict__ gcnt) {
    int c = threadIdx.x;
    int r0 = blockIdx.x * 256;
    int r1 = min(r0 + 256, NN);
    float acc = 0.f;
    int gcur = batch[r0];
    for (int n = r0; n < r1; n++) {
        int g = batch[n];
        if (g != gcur) {
            atomicAdd(&gsum[(size_t)gcur * HC + c], acc);
            acc = 0.f; gcur = g;
        }
        acc += x[(size_t)n * HC + c];
    }
    atomicAdd(&gsum[(size_t)gcur * HC + c], acc);
    if (c == 0) {
        int cnt = 0; gcur = batch[r0];
        for (int n = r0; n < r1; n++) {
            int g = batch[n];
            if (g != gcur) {
                atomicAdd(&gcnt[gcur], (float)cnt);
                cnt = 0; gcur = g;
            }
            cnt++;
        }
        atomicAdd(&gcnt[gcur], (float)cnt);
    }
}

// glob[g] = LN(gmean @ graph_W + graph_b); one wave (block of 64) per graph
__global__ void glob_kernel(const float* __restrict__ gsum, const float* __restrict__ gcnt,
                            const float* __restrict__ W, const float* __restrict__ bias,
                            const float* __restrict__ g, const float* __restrict__ b,
                            float* __restrict__ out) {
    int gi = blockIdx.x;
    int lane = threadIdx.x;
    float inv = 1.f / fmaxf(gcnt[gi], 1.f);
    float acc = 0.f;
    for (int k = 0; k < HC; k++)
        acc += (gsum[(size_t)gi * HC + k] * inv) * W[(size_t)k * ND + lane];
    acc += bias[lane];
    float s = acc;
    #pragma unroll
    for (int o = 32; o >= 1; o >>= 1) s += __shfl_xor(s, o);
    float mu = s * (1.f / 64.f);
    float dv = acc - mu;
    float q = dv * dv;
    #pragma unroll
    for (int o = 32; o >= 1; o >>= 1) q += __shfl_xor(q, o);
    float var = q * (1.f / 64.f);
    out[(size_t)gi * ND + lane] = dv * rsqrtf(var + LN_EPS) * g[lane] + b[lane];
}

// ---------------------------------------------------------------------------
extern "C" void kernel_launch(void* const* d_in, const int* in_sizes, int n_in,
                              void* d_out, int out_size, void* d_ws, size_t ws_size,
                              hipStream_t stream) {
    (void)in_sizes; (void)n_in; (void)out_size; (void)ws_size;
    const float* node_feature = (const float*)d_in[0];
    const int*   edge_index   = (const int*)d_in[1];
    const float* edge_feature = (const float*)d_in[2];
    const int*   batch        = (const int*)d_in[3];
    const float* Wl0   = (const float*)d_in[4];
    const float* bl0   = (const float*)d_in[5];
    const float* Wr0   = (const float*)d_in[6];
    const float* br0   = (const float*)d_in[7];
    const float* We0   = (const float*)d_in[8];
    const float* att0  = (const float*)d_in[9];
    const float* bias0 = (const float*)d_in[10];
    const float* Wl1   = (const float*)d_in[11];
    const float* bl1   = (const float*)d_in[12];
    const float* Wr1   = (const float*)d_in[13];
    const float* br1   = (const float*)d_in[14];
    const float* We1   = (const float*)d_in[15];
    const float* att1  = (const float*)d_in[16];
    const float* bias1 = (const float*)d_in[17];
    const float* node_W  = (const float*)d_in[18];
    const float* node_b  = (const float*)d_in[19];
    const float* graph_W = (const float*)d_in[20];
    const float* graph_b = (const float*)d_in[21];
    const float* nn_g = (const float*)d_in[22];
    const float* nn_b = (const float*)d_in[23];
    const float* gn_g = (const float*)d_in[24];
    const float* gn_b = (const float*)d_in[25];

    const int* src = edge_index;
    const int* dst = edge_index + NE;

    char* p = (char*)d_ws;
    auto carve = [&](size_t bytes) {
        char* r = p;
        p += (bytes + 255) & ~(size_t)255;
        return r;
    };
    int*   row_ptr   = (int*)carve((NN + 1) * sizeof(int));
    int*   cursor    = (int*)carve(NN * sizeof(int));
    int*   csr_src   = (int*)carve((size_t)NE * sizeof(int));
    int*   csr_eid   = (int*)carve((size_t)NE * sizeof(int));
    float* loop_attr = (float*)carve((size_t)NN * EDIM * sizeof(float));
    float* xl        = (float*)carve((size_t)NN * HC * sizeof(float));
    float* xr        = (float*)carve((size_t)NN * HC * sizeof(float));
    float* xb        = (float*)carve((size_t)NN * HC * sizeof(float));
    float* alpha     = (float*)carve((size_t)(NE + NN) * NH * sizeof(float));
    float* gsum      = (float*)carve((size_t)(NGG * HC + NGG) * sizeof(float));
    float* gcnt      = gsum + (size_t)NGG * HC;

    hipMemsetAsync(cursor, 0, NN * sizeof(int), stream);
    hipMemsetAsync(gsum, 0, (NGG * HC + NGG) * sizeof(float), stream);

    // CSR + loop_attr (layer-independent)
    count_deg<<<(NE + 255) / 256, 256, 0, stream>>>(dst, cursor);
    scan_deg<<<1, 1024, 0, stream>>>(cursor, row_ptr);
    fill_csr<<<(NE + 255) / 256, 256, 0, stream>>>(src, dst, cursor, csr_src, csr_eid);
    loop_attr_kernel<<<(NN * EDIM + 255) / 256, 256, 0, stream>>>(edge_feature, row_ptr, csr_eid, loop_attr);

    dim3 gHC(HC / 64, (NN + 127) / 128);
    // Layer 0
    gemm_bias<<<gHC, 256, 0, stream>>>(node_feature, Wl0, bl0, xl, NN, DIN, HC);
    gemm_bias<<<gHC, 256, 0, stream>>>(node_feature, Wr0, br0, xr, NN, DIN, HC);
    alpha_kernel<<<2048, 256, 0, stream>>>(src, dst, edge_feature, loop_attr, xl, xr, We0, att0, alpha);
    aggregate_kernel<<<(NN + 3) / 4, 256, 0, stream>>>(xl, alpha, row_ptr, csr_src, csr_eid, bias0, xb, 1);
    // Layer 1
    gemm_bias<<<gHC, 256, 0, stream>>>(xb, Wl1, bl1, xl, NN, HC, HC);
    gemm_bias<<<gHC, 256, 0, stream>>>(xb, Wr1, br1, xr, NN, HC, HC);
    alpha_kernel<<<2048, 256, 0, stream>>>(src, dst, edge_feature, loop_attr, xl, xr, We1, att1, alpha);
    aggregate_kernel<<<(NN + 3) / 4, 256, 0, stream>>>(xl, alpha, row_ptr, csr_src, csr_eid, bias1, xb, 0);

    // Heads
    float* out_local = (float*)d_out;
    float* out_glob  = out_local + (size_t)NN * ND;
    dim3 gND(ND / 64, (NN + 127) / 128);
    gemm_bias<<<gND, 256, 0, stream>>>(xb, node_W, node_b, out_local, NN, HC, ND);
    ln_rows<<<(NN + 3) / 4, 256, 0, stream>>>(out_local, nn_g, nn_b, NN);
    graph_sum<<<(NN + 255) / 256, 256, 0, stream>>>(xb, batch, gsum, gcnt);
    glob_kernel<<<NGG, 64, 0, stream>>>(gsum, gcnt, graph_W, graph_b, gn_g, gn_b, out_glob);
}

// Round 2
// 1237.553 us; speedup vs baseline: 2.2428x; 2.2428x over previous
//
#include <hip/hip_runtime.h>
#include <cstdint>
#include <cstddef>

#define NN   50000
#define NE   500000
#define DIN  64
#define EDIM 32
#define NH   4
#define NC   64
#define HC   256   // NH*NC
#define NGG  64
#define ND   64
#define LN_EPS 1e-5f

// ---------------------------------------------------------------------------
// CSR build: degree count -> single-block scan -> fill
// ---------------------------------------------------------------------------
__global__ void count_deg(const int* __restrict__ dst, int* __restrict__ deg) {
    int e = blockIdx.x * blockDim.x + threadIdx.x;
    if (e < NE) atomicAdd(&deg[dst[e]], 1);
}

// cursor holds deg on entry; on exit cursor[n] = row start, row_ptr filled.
__global__ void scan_deg(int* __restrict__ cursor, int* __restrict__ row_ptr) {
    __shared__ int sums[1024];
    const int T = 1024;
    const int chunk = (NN + T - 1) / T;  // 49
    int t = threadIdx.x;
    int lo = t * chunk, hi = min(lo + chunk, NN);
    int s = 0;
    for (int i = lo; i < hi; i++) s += cursor[i];
    sums[t] = s;
    __syncthreads();
    for (int off = 1; off < T; off <<= 1) {   // inclusive Hillis-Steele
        int v = (t >= off) ? sums[t - off] : 0;
        __syncthreads();
        sums[t] += v;
        __syncthreads();
    }
    int base = (t == 0) ? 0 : sums[t - 1];
    for (int i = lo; i < hi; i++) {
        int d = cursor[i];
        row_ptr[i] = base;
        cursor[i] = base;
        base += d;
    }
    if (t == 0) row_ptr[NN] = NE;
}

__global__ void fill_csr(const int* __restrict__ src, const int* __restrict__ dst,
                         int* __restrict__ cursor, int* __restrict__ csr_src,
                         int* __restrict__ csr_eid) {
    int e = blockIdx.x * blockDim.x + threadIdx.x;
    if (e < NE) {
        int d = dst[e];
        int pos = atomicAdd(&cursor[d], 1);
        csr_src[pos] = src[e];
        csr_eid[pos] = e;
    }
}

// loop_attr[n][c] = mean over incident (dst) edges of edge_feature, 0 if deg==0
__global__ void loop_attr_kernel(const float* __restrict__ ef, const int* __restrict__ row_ptr,
                                 const int* __restrict__ csr_eid, float* __restrict__ loop_attr) {
    int idx = blockIdx.x * blockDim.x + threadIdx.x;
    if (idx >= NN * EDIM) return;
    int n = idx >> 5, c = idx & 31;
    int s = row_ptr[n], e = row_ptr[n + 1];
    float acc = 0.f;
    for (int j = s; j < e; j++) acc += ef[(size_t)csr_eid[j] * EDIM + c];
    int d = e - s;
    loop_attr[(size_t)n * EDIM + c] = acc / (float)max(d, 1);
}

// ---------------------------------------------------------------------------
// fp32 GEMM + bias: C[M,Nn] = A[M,K] @ B[K,Nn] + bias.  BM=128 BN=64 BK=16,
// 256 threads, 8x4 microtile. K%16==0, Nn%64==0 assumed.
// ---------------------------------------------------------------------------
__global__ void gemm_bias(const float* __restrict__ A, const float* __restrict__ B,
                          const float* __restrict__ bias, float* __restrict__ Cout,
                          int M, int K, int Nn) {
    __shared__ __align__(16) float As[16][132];
    __shared__ __align__(16) float Bs[16][64];
    int tid = threadIdx.x;
    int tx = tid & 15;        // col group (4 cols)
    int ty = tid >> 4;        // row group (8 rows)
    int rowBase = blockIdx.y * 128;
    int colBase = blockIdx.x * 64;
    float acc[8][4] = {};
    for (int kk = 0; kk < K; kk += 16) {
        #pragma unroll
        for (int t = 0; t < 2; t++) {            // A tile: 128x16 = 512 float4
            int f = tid + 256 * t;
            int r = f >> 2;
            int k4 = (f & 3) * 4;
            float4 v = make_float4(0.f, 0.f, 0.f, 0.f);
            int row = rowBase + r;
            if (row < M) v = *(const float4*)(A + (size_t)row * K + kk + k4);
            As[k4 + 0][r] = v.x; As[k4 + 1][r] = v.y;
            As[k4 + 2][r] = v.z; As[k4 + 3][r] = v.w;
        }
        {                                        // B tile: 16x64
            int k = tid >> 4;
            int c4 = (tid & 15) * 4;
            *(float4*)&Bs[k][c4] = *(const float4*)(B + (size_t)(kk + k) * Nn + colBase + c4);
        }
        __syncthreads();
        #pragma unroll
        for (int k = 0; k < 16; k++) {
            float4 a0 = *(const float4*)&As[k][ty * 8];
            float4 a1 = *(const float4*)&As[k][ty * 8 + 4];
            float4 b4 = *(const float4*)&Bs[k][tx * 4];
            float av[8] = {a0.x, a0.y, a0.z, a0.w, a1.x, a1.y, a1.z, a1.w};
            float bv[4] = {b4.x, b4.y, b4.z, b4.w};
            #pragma unroll
            for (int i = 0; i < 8; i++)
                #pragma unroll
                for (int j = 0; j < 4; j++)
                    acc[i][j] += av[i] * bv[j];
        }
        __syncthreads();
    }
    float4 bb = *(const float4*)(bias + colBase + tx * 4);
    #pragma unroll
    for (int i = 0; i < 8; i++) {
        int row = rowBase + ty * 8 + i;
        if (row < M) {
            float4 r = make_float4(acc[i][0] + bb.x, acc[i][1] + bb.y,
                                   acc[i][2] + bb.z, acc[i][3] + bb.w);
            *(float4*)(Cout + (size_t)row * Nn + colBase + tx * 4) = r;
        }
    }
}

// ---------------------------------------------------------------------------
// Fused GATv2 attention + online-softmax aggregation.
// One wave per node (persistent, grid-stride). lane owns channels
// hc = 4*lane..4*lane+3 (head h = lane>>4). We held in 128 VGPRs/lane;
// __launch_bounds__(256,2) caps at 256 VGPR so it does NOT spill.
// Per edge: gather xl[src] once, use for both score and accumulation.
// out[n] = sum_e softmax(alpha)_e * xl[src_e] + bias  (optional relu)
// ---------------------------------------------------------------------------
__global__ __launch_bounds__(256, 2)
void gat_fused(const float* __restrict__ xl, const float* __restrict__ xr,
               const float* __restrict__ ef, const float* __restrict__ loop_attr,
               const int* __restrict__ row_ptr, const int* __restrict__ csr_src,
               const int* __restrict__ csr_eid,
               const float* __restrict__ We, const float* __restrict__ att,
               const float* __restrict__ bias, float* __restrict__ out, int do_relu) {
    int lane = threadIdx.x & 63;
    int wv = threadIdx.x >> 6;
    int wid = blockIdx.x * 4 + wv;
    int nw = gridDim.x * 4;

    float4 wreg[32];
    #pragma unroll
    for (int k = 0; k < 32; k++)
        wreg[k] = *(const float4*)(We + k * HC + 4 * lane);
    int h = lane >> 4;
    float4 attv = *(const float4*)(att + h * NC + 4 * (lane & 15));
    float4 bb = *(const float4*)(bias + 4 * lane);

    for (int n0 = wid; n0 < NN; n0 += nw) {
        int n = __builtin_amdgcn_readfirstlane(n0);
        float4 xrv = *(const float4*)(xr + (size_t)n * HC + 4 * lane);
        int s0 = row_ptr[n], e0 = row_ptr[n + 1];

        // ---- self-loop item ----
        float ea[32];
        {
            const float* eap = loop_attr + (size_t)n * EDIM;
            #pragma unroll
            for (int q = 0; q < 8; q++) {
                float4 t = *(const float4*)(eap + 4 * q);
                ea[4 * q] = t.x; ea[4 * q + 1] = t.y; ea[4 * q + 2] = t.z; ea[4 * q + 3] = t.w;
            }
        }
        float4 xlv = *(const float4*)(xl + (size_t)n * HC + 4 * lane);
        float4 ee = make_float4(0.f, 0.f, 0.f, 0.f);
        #pragma unroll
        for (int k = 0; k < 32; k++) {
            ee.x += ea[k] * wreg[k].x; ee.y += ea[k] * wreg[k].y;
            ee.z += ea[k] * wreg[k].z; ee.w += ea[k] * wreg[k].w;
        }
        float m0 = xlv.x + xrv.x + ee.x; m0 = m0 > 0.f ? m0 : 0.2f * m0;
        float m1 = xlv.y + xrv.y + ee.y; m1 = m1 > 0.f ? m1 : 0.2f * m1;
        float m2 = xlv.z + xrv.z + ee.z; m2 = m2 > 0.f ? m2 : 0.2f * m2;
        float m3 = xlv.w + xrv.w + ee.w; m3 = m3 > 0.f ? m3 : 0.2f * m3;
        float p = m0 * attv.x + m1 * attv.y + m2 * attv.z + m3 * attv.w;
        p += __shfl_xor(p, 1);
        p += __shfl_xor(p, 2);
        p += __shfl_xor(p, 4);
        p += __shfl_xor(p, 8);
        float mx = p;
        float denom = 1.f;  // exp(p - mx)
        float4 acc = xlv;

        // ---- incident edges ----
        for (int j = s0; j < e0; j++) {
            int s = __builtin_amdgcn_readfirstlane(csr_src[j]);
            int eid = __builtin_amdgcn_readfirstlane(csr_eid[j]);
            const float* eap = ef + (size_t)eid * EDIM;
            #pragma unroll
            for (int q = 0; q < 8; q++) {
                float4 t = *(const float4*)(eap + 4 * q);
                ea[4 * q] = t.x; ea[4 * q + 1] = t.y; ea[4 * q + 2] = t.z; ea[4 * q + 3] = t.w;
            }
            xlv = *(const float4*)(xl + (size_t)s * HC + 4 * lane);
            ee = make_float4(0.f, 0.f, 0.f, 0.f);
            #pragma unroll
            for (int k = 0; k < 32; k++) {
                ee.x += ea[k] * wreg[k].x; ee.y += ea[k] * wreg[k].y;
                ee.z += ea[k] * wreg[k].z; ee.w += ea[k] * wreg[k].w;
            }
            m0 = xlv.x + xrv.x + ee.x; m0 = m0 > 0.f ? m0 : 0.2f * m0;
            m1 = xlv.y + xrv.y + ee.y; m1 = m1 > 0.f ? m1 : 0.2f * m1;
            m2 = xlv.z + xrv.z + ee.z; m2 = m2 > 0.f ? m2 : 0.2f * m2;
            m3 = xlv.w + xrv.w + ee.w; m3 = m3 > 0.f ? m3 : 0.2f * m3;
            p = m0 * attv.x + m1 * attv.y + m2 * attv.z + m3 * attv.w;
            p += __shfl_xor(p, 1);
            p += __shfl_xor(p, 2);
            p += __shfl_xor(p, 4);
            p += __shfl_xor(p, 8);
            float nm = fmaxf(mx, p);
            float sc = __expf(mx - nm);
            float a = __expf(p - nm);
            denom = denom * sc + a;
            acc.x = acc.x * sc + xlv.x * a;
            acc.y = acc.y * sc + xlv.y * a;
            acc.z = acc.z * sc + xlv.z * a;
            acc.w = acc.w * sc + xlv.w * a;
            mx = nm;
        }

        float inv = 1.f / denom;
        float4 r = make_float4(acc.x * inv + bb.x, acc.y * inv + bb.y,
                               acc.z * inv + bb.z, acc.w * inv + bb.w);
        if (do_relu) {
            r.x = fmaxf(r.x, 0.f); r.y = fmaxf(r.y, 0.f);
            r.z = fmaxf(r.z, 0.f); r.w = fmaxf(r.w, 0.f);
        }
        *(float4*)(out + (size_t)n * HC + 4 * lane) = r;
    }
}

// ---------------------------------------------------------------------------
// In-place LayerNorm over rows of width 64 (one wave per row)
// ---------------------------------------------------------------------------
__global__ void ln_rows(float* __restrict__ y, const float* __restrict__ g,
                        const float* __restrict__ b, int M) {
    int lane = threadIdx.x & 63;
    int wv = threadIdx.x >> 6;
    int n = blockIdx.x * 4 + wv;
    if (n >= M) return;
    float v = y[(size_t)n * 64 + lane];
    float s = v;
    #pragma unroll
    for (int o = 32; o >= 1; o >>= 1) s += __shfl_xor(s, o);
    float mu = s * (1.f / 64.f);
    float dv = v - mu;
    float q = dv * dv;
    #pragma unroll
    for (int o = 32; o >= 1; o >>= 1) q += __shfl_xor(q, o);
    float var = q * (1.f / 64.f);
    y[(size_t)n * 64 + lane] = dv * rsqrtf(var + LN_EPS) * g[lane] + b[lane];
}

// ---------------------------------------------------------------------------
// Graph mean pre-reduction exploiting sorted batch
// ---------------------------------------------------------------------------
__global__ void graph_sum(const float* __restrict__ x, const int* __restrict__ batch,
                          float* __restrict__ gsum, float* __restrict__ gcnt) {
    int c = threadIdx.x;
    int r0 = blockIdx.x * 256;
    int r1 = min(r0 + 256, NN);
    float acc = 0.f;
    int gcur = batch[r0];
    for (int n = r0; n < r1; n++) {
        int g = batch[n];
        if (g != gcur) {
            atomicAdd(&gsum[(size_t)gcur * HC + c], acc);
            acc = 0.f; gcur = g;
        }
        acc += x[(size_t)n * HC + c];
    }
    atomicAdd(&gsum[(size_t)gcur * HC + c], acc);
    if (c == 0) {
        int cnt = 0; gcur = batch[r0];
        for (int n = r0; n < r1; n++) {
            int g = batch[n];
            if (g != gcur) {
                atomicAdd(&gcnt[gcur], (float)cnt);
                cnt = 0; gcur = g;
            }
            cnt++;
        }
        atomicAdd(&gcnt[gcur], (float)cnt);
    }
}

// glob[g] = LN(gmean @ graph_W + graph_b); one wave (block of 64) per graph
__global__ void glob_kernel(const float* __restrict__ gsum, const float* __restrict__ gcnt,
                            const float* __restrict__ W, const float* __restrict__ bias,
                            const float* __restrict__ g, const float* __restrict__ b,
                            float* __restrict__ out) {
    int gi = blockIdx.x;
    int lane = threadIdx.x;
    float inv = 1.f / fmaxf(gcnt[gi], 1.f);
    float acc = 0.f;
    for (int k = 0; k < HC; k++)
        acc += (gsum[(size_t)gi * HC + k] * inv) * W[(size_t)k * ND + lane];
    acc += bias[lane];
    float s = acc;
    #pragma unroll
    for (int o = 32; o >= 1; o >>= 1) s += __shfl_xor(s, o);
    float mu = s * (1.f / 64.f);
    float dv = acc - mu;
    float q = dv * dv;
    #pragma unroll
    for (int o = 32; o >= 1; o >>= 1) q += __shfl_xor(q, o);
    float var = q * (1.f / 64.f);
    out[(size_t)gi * ND + lane] = dv * rsqrtf(var + LN_EPS) * g[lane] + b[lane];
}

// ---------------------------------------------------------------------------
extern "C" void kernel_launch(void* const* d_in, const int* in_sizes, int n_in,
                              void* d_out, int out_size, void* d_ws, size_t ws_size,
                              hipStream_t stream) {
    (void)in_sizes; (void)n_in; (void)out_size; (void)ws_size;
    const float* node_feature = (const float*)d_in[0];
    const int*   edge_index   = (const int*)d_in[1];
    const float* edge_feature = (const float*)d_in[2];
    const int*   batch        = (const int*)d_in[3];
    const float* Wl0   = (const float*)d_in[4];
    const float* bl0   = (const float*)d_in[5];
    const float* Wr0   = (const float*)d_in[6];
    const float* br0   = (const float*)d_in[7];
    const float* We0   = (const float*)d_in[8];
    const float* att0  = (const float*)d_in[9];
    const float* bias0 = (const float*)d_in[10];
    const float* Wl1   = (const float*)d_in[11];
    const float* bl1   = (const float*)d_in[12];
    const float* Wr1   = (const float*)d_in[13];
    const float* br1   = (const float*)d_in[14];
    const float* We1   = (const float*)d_in[15];
    const float* att1  = (const float*)d_in[16];
    const float* bias1 = (const float*)d_in[17];
    const float* node_W  = (const float*)d_in[18];
    const float* node_b  = (const float*)d_in[19];
    const float* graph_W = (const float*)d_in[20];
    const float* graph_b = (const float*)d_in[21];
    const float* nn_g = (const float*)d_in[22];
    const float* nn_b = (const float*)d_in[23];
    const float* gn_g = (const float*)d_in[24];
    const float* gn_b = (const float*)d_in[25];

    const int* src = edge_index;
    const int* dst = edge_index + NE;

    char* p = (char*)d_ws;
    auto carve = [&](size_t bytes) {
        char* r = p;
        p += (bytes + 255) & ~(size_t)255;
        return r;
    };
    int*   row_ptr   = (int*)carve((NN + 1) * sizeof(int));
    int*   cursor    = (int*)carve(NN * sizeof(int));
    int*   csr_src   = (int*)carve((size_t)NE * sizeof(int));
    int*   csr_eid   = (int*)carve((size_t)NE * sizeof(int));
    float* loop_attr = (float*)carve((size_t)NN * EDIM * sizeof(float));
    float* xl        = (float*)carve((size_t)NN * HC * sizeof(float));
    float* xr        = (float*)carve((size_t)NN * HC * sizeof(float));
    float* xb        = (float*)carve((size_t)NN * HC * sizeof(float));
    float* gsum      = (float*)carve((size_t)(NGG * HC + NGG) * sizeof(float));
    float* gcnt      = gsum + (size_t)NGG * HC;

    hipMemsetAsync(cursor, 0, NN * sizeof(int), stream);
    hipMemsetAsync(gsum, 0, (NGG * HC + NGG) * sizeof(float), stream);

    // CSR + loop_attr (layer-independent)
    count_deg<<<(NE + 255) / 256, 256, 0, stream>>>(dst, cursor);
    scan_deg<<<1, 1024, 0, stream>>>(cursor, row_ptr);
    fill_csr<<<(NE + 255) / 256, 256, 0, stream>>>(src, dst, cursor, csr_src, csr_eid);
    loop_attr_kernel<<<(NN * EDIM + 255) / 256, 256, 0, stream>>>(edge_feature, row_ptr, csr_eid, loop_attr);

    dim3 gHC(HC / 64, (NN + 127) / 128);
    // Layer 0
    gemm_bias<<<gHC, 256, 0, stream>>>(node_feature, Wl0, bl0, xl, NN, DIN, HC);
    gemm_bias<<<gHC, 256, 0, stream>>>(node_feature, Wr0, br0, xr, NN, DIN, HC);
    gat_fused<<<1024, 256, 0, stream>>>(xl, xr, edge_feature, loop_attr, row_ptr, csr_src, csr_eid,
                                        We0, att0, bias0, xb, 1);
    // Layer 1
    gemm_bias<<<gHC, 256, 0, stream>>>(xb, Wl1, bl1, xl, NN, HC, HC);
    gemm_bias<<<gHC, 256, 0, stream>>>(xb, Wr1, br1, xr, NN, HC, HC);
    gat_fused<<<1024, 256, 0, stream>>>(xl, xr, edge_feature, loop_attr, row_ptr, csr_src, csr_eid,
                                        We1, att1, bias1, xb, 0);

    // Heads
    float* out_local = (float*)d_out;
    float* out_glob  = out_local + (size_t)NN * ND;
    dim3 gND(ND / 64, (NN + 127) / 128);
    gemm_bias<<<gND, 256, 0, stream>>>(xb, node_W, node_b, out_local, NN, HC, ND);
    ln_rows<<<(NN + 3) / 4, 256, 0, stream>>>(out_local, nn_g, nn_b, NN);
    graph_sum<<<(NN + 255) / 256, 256, 0, stream>>>(xb, batch, gsum, gcnt);
    glob_kernel<<<NGG, 64, 0, stream>>>(gsum, gcnt, graph_W, graph_b, gn_g, gn_b, out_glob);
}

// Round 3
// 1065.817 us; speedup vs baseline: 2.6041x; 1.1611x over previous
//
#include <hip/hip_runtime.h>
#include <cstdint>
#include <cstddef>

#define NN   50000
#define NE   500000
#define DIN  64
#define EDIM 32
#define NH   4
#define NC   64
#define HC   256   // NH*NC
#define NGG  64
#define ND   64
#define LN_EPS 1e-5f

typedef __attribute__((ext_vector_type(8))) short bf16x8;
typedef __attribute__((ext_vector_type(4))) float f32x4;
typedef __attribute__((ext_vector_type(4))) unsigned short u16x4;

__device__ __forceinline__ unsigned short f2bf(float x) {
    unsigned u = __float_as_uint(x);
    unsigned r = (u + 0x7FFFu + ((u >> 16) & 1u)) >> 16;
    return (unsigned short)r;
}
__device__ __forceinline__ float bf2f(unsigned short h) {
    return __uint_as_float(((unsigned)h) << 16);
}

// ---------------------------------------------------------------------------
// CSR build: degree count -> single-block scan -> fill
// ---------------------------------------------------------------------------
__global__ void count_deg(const int* __restrict__ dst, int* __restrict__ deg) {
    int e = blockIdx.x * blockDim.x + threadIdx.x;
    if (e < NE) atomicAdd(&deg[dst[e]], 1);
}

__global__ void scan_deg(int* __restrict__ cursor, int* __restrict__ row_ptr) {
    __shared__ int sums[1024];
    const int T = 1024;
    const int chunk = (NN + T - 1) / T;  // 49
    int t = threadIdx.x;
    int lo = t * chunk, hi = min(lo + chunk, NN);
    int s = 0;
    for (int i = lo; i < hi; i++) s += cursor[i];
    sums[t] = s;
    __syncthreads();
    for (int off = 1; off < T; off <<= 1) {
        int v = (t >= off) ? sums[t - off] : 0;
        __syncthreads();
        sums[t] += v;
        __syncthreads();
    }
    int base = (t == 0) ? 0 : sums[t - 1];
    for (int i = lo; i < hi; i++) {
        int d = cursor[i];
        row_ptr[i] = base;
        cursor[i] = base;
        base += d;
    }
    if (t == 0) row_ptr[NN] = NE;
}

__global__ void fill_csr(const int* __restrict__ src, const int* __restrict__ dst,
                         int* __restrict__ cursor, int* __restrict__ csr_src,
                         int* __restrict__ csr_eid) {
    int e = blockIdx.x * blockDim.x + threadIdx.x;
    if (e < NE) {
        int d = dst[e];
        int pos = atomicAdd(&cursor[d], 1);
        csr_src[pos] = src[e];
        csr_eid[pos] = e;
    }
}

__global__ void loop_attr_kernel(const float* __restrict__ ef, const int* __restrict__ row_ptr,
                                 const int* __restrict__ csr_eid, float* __restrict__ loop_attr) {
    int idx = blockIdx.x * blockDim.x + threadIdx.x;
    if (idx >= NN * EDIM) return;
    int n = idx >> 5, c = idx & 31;
    int s = row_ptr[n], e = row_ptr[n + 1];
    float acc = 0.f;
    for (int j = s; j < e; j++) acc += ef[(size_t)csr_eid[j] * EDIM + c];
    int d = e - s;
    loop_attr[(size_t)n * EDIM + c] = acc / (float)max(d, 1);
}

// ---------------------------------------------------------------------------
// Weight pre-pass: W[K][N] fp32 -> transposed bf16 hi/lo [N][K]
// ---------------------------------------------------------------------------
__global__ void conv_wt(const float* __restrict__ W, unsigned short* __restrict__ hi,
                        unsigned short* __restrict__ lo, int K, int Nn) {
    int idx = blockIdx.x * blockDim.x + threadIdx.x;
    if (idx >= K * Nn) return;
    int k = idx / Nn, n = idx - k * Nn;
    float x = W[idx];
    unsigned short h = f2bf(x);
    unsigned short l = f2bf(x - bf2f(h));
    hi[(size_t)n * K + k] = h;
    lo[(size_t)n * K + k] = l;
}

// ---------------------------------------------------------------------------
// MFMA split-bf16 GEMM: C[M,Nn] = A[M,K] @ B[K,Nn] + bias.
// A fp32 row-major (split to bf16 hi/lo during LDS staging).
// B pre-split, pre-transposed: Bth/Btl are [Nn][K] bf16.
// Tile 64x64x32, 256 threads (4 waves), wave w owns rows w*16..w*16+15.
// 3 MFMA per 16x16 tile (AhBh + AlBh + AhBl) -> fp32-class accuracy.
// ---------------------------------------------------------------------------
#define LDT 40   // padded k-stride (elems); 80 B, 16B-aligned, ~2-way banks

__global__ __launch_bounds__(256, 2)
void gemm_mfma(const float* __restrict__ A, const unsigned short* __restrict__ Bth,
               const unsigned short* __restrict__ Btl, const float* __restrict__ bias,
               float* __restrict__ C, int M, int K, int Nn) {
    __shared__ unsigned short Ah[64][LDT], Al[64][LDT];
    __shared__ unsigned short Bh[64][LDT], Bl[64][LDT];
    int tid = threadIdx.x;
    int lane = tid & 63, w = tid >> 6;
    int m = lane & 15, q = lane >> 4;
    int rowBase = blockIdx.y * 64, colBase = blockIdx.x * 64;
    f32x4 acc[4];
    #pragma unroll
    for (int ct = 0; ct < 4; ct++) acc[ct] = (f32x4){0.f, 0.f, 0.f, 0.f};

    for (int kk = 0; kk < K; kk += 32) {
        // ---- stage A: 64 rows x 32 k fp32 -> hi/lo bf16 ----
        #pragma unroll
        for (int u = 0; u < 2; u++) {
            int f = tid + 256 * u;      // 0..511
            int r = f >> 3;             // 0..63
            int k4 = (f & 7) * 4;
            int row = rowBase + r;
            float4 v = make_float4(0.f, 0.f, 0.f, 0.f);
            if (row < M) v = *(const float4*)(A + (size_t)row * K + kk + k4);
            unsigned short h0 = f2bf(v.x), h1 = f2bf(v.y), h2 = f2bf(v.z), h3 = f2bf(v.w);
            unsigned short l0 = f2bf(v.x - bf2f(h0)), l1 = f2bf(v.y - bf2f(h1));
            unsigned short l2 = f2bf(v.z - bf2f(h2)), l3 = f2bf(v.w - bf2f(h3));
            *(u16x4*)&Ah[r][k4] = (u16x4){h0, h1, h2, h3};
            *(u16x4*)&Al[r][k4] = (u16x4){l0, l1, l2, l3};
        }
        // ---- stage B: pre-transposed bf16 [N][K], vectorized 16B copies ----
        {
            int n = tid >> 2;           // 0..63
            int ch = tid & 3;           // 16B chunk within 32-k row
            size_t goff = (size_t)(colBase + n) * K + kk + ch * 8;
            *(bf16x8*)&Bh[n][ch * 8] = *(const bf16x8*)(Bth + goff);
            *(bf16x8*)&Bl[n][ch * 8] = *(const bf16x8*)(Btl + goff);
        }
        __syncthreads();
        bf16x8 a_h = *(const bf16x8*)&Ah[w * 16 + m][q * 8];
        bf16x8 a_l = *(const bf16x8*)&Al[w * 16 + m][q * 8];
        #pragma unroll
        for (int ct = 0; ct < 4; ct++) {
            bf16x8 b_h = *(const bf16x8*)&Bh[ct * 16 + m][q * 8];
            bf16x8 b_l = *(const bf16x8*)&Bl[ct * 16 + m][q * 8];
            acc[ct] = __builtin_amdgcn_mfma_f32_16x16x32_bf16(a_h, b_h, acc[ct], 0, 0, 0);
            acc[ct] = __builtin_amdgcn_mfma_f32_16x16x32_bf16(a_l, b_h, acc[ct], 0, 0, 0);
            acc[ct] = __builtin_amdgcn_mfma_f32_16x16x32_bf16(a_h, b_l, acc[ct], 0, 0, 0);
        }
        __syncthreads();
    }
    // epilogue: D[row=(q*4+r)][col=m] per 16x16 tile
    #pragma unroll
    for (int ct = 0; ct < 4; ct++) {
        int col = colBase + ct * 16 + m;
        float bb = bias[col];
        #pragma unroll
        for (int r = 0; r < 4; r++) {
            int row = rowBase + w * 16 + q * 4 + r;
            if (row < M) C[(size_t)row * Nn + col] = acc[ct][r] + bb;
        }
    }
}

// ---------------------------------------------------------------------------
// Fused GATv2 attention + online-softmax aggregation, edge loop unrolled x2.
// ---------------------------------------------------------------------------
__device__ __forceinline__ void load_ea(const float* __restrict__ p, float ea[32]) {
    #pragma unroll
    for (int qq = 0; qq < 8; qq++) {
        float4 t = *(const float4*)(p + 4 * qq);
        ea[4 * qq] = t.x; ea[4 * qq + 1] = t.y; ea[4 * qq + 2] = t.z; ea[4 * qq + 3] = t.w;
    }
}

__device__ __forceinline__ float gat_score(const float ea[32], const float4 wreg[32],
                                           float4 xlv, float4 xrv, float4 attv) {
    float4 ee = make_float4(0.f, 0.f, 0.f, 0.f);
    #pragma unroll
    for (int k = 0; k < 32; k++) {
        ee.x += ea[k] * wreg[k].x; ee.y += ea[k] * wreg[k].y;
        ee.z += ea[k] * wreg[k].z; ee.w += ea[k] * wreg[k].w;
    }
    float m0 = xlv.x + xrv.x + ee.x; m0 = m0 > 0.f ? m0 : 0.2f * m0;
    float m1 = xlv.y + xrv.y + ee.y; m1 = m1 > 0.f ? m1 : 0.2f * m1;
    float m2 = xlv.z + xrv.z + ee.z; m2 = m2 > 0.f ? m2 : 0.2f * m2;
    float m3 = xlv.w + xrv.w + ee.w; m3 = m3 > 0.f ? m3 : 0.2f * m3;
    float p = m0 * attv.x + m1 * attv.y + m2 * attv.z + m3 * attv.w;
    p += __shfl_xor(p, 1);
    p += __shfl_xor(p, 2);
    p += __shfl_xor(p, 4);
    p += __shfl_xor(p, 8);
    return p;
}

__global__ __launch_bounds__(256, 2)
void gat_fused(const float* __restrict__ xl, const float* __restrict__ xr,
               const float* __restrict__ ef, const float* __restrict__ loop_attr,
               const int* __restrict__ row_ptr, const int* __restrict__ csr_src,
               const int* __restrict__ csr_eid,
               const float* __restrict__ We, const float* __restrict__ att,
               const float* __restrict__ bias, float* __restrict__ out, int do_relu) {
    int lane = threadIdx.x & 63;
    int wv = threadIdx.x >> 6;
    int wid = blockIdx.x * 4 + wv;
    int nw = gridDim.x * 4;

    float4 wreg[32];
    #pragma unroll
    for (int k = 0; k < 32; k++)
        wreg[k] = *(const float4*)(We + k * HC + 4 * lane);
    int h = lane >> 4;
    float4 attv = *(const float4*)(att + h * NC + 4 * (lane & 15));
    float4 bb = *(const float4*)(bias + 4 * lane);

    for (int n0 = wid; n0 < NN; n0 += nw) {
        int n = __builtin_amdgcn_readfirstlane(n0);
        float4 xrv = *(const float4*)(xr + (size_t)n * HC + 4 * lane);
        int s0 = row_ptr[n], e0 = row_ptr[n + 1];

        // ---- self-loop ----
        float ea[32];
        load_ea(loop_attr + (size_t)n * EDIM, ea);
        float4 xlv = *(const float4*)(xl + (size_t)n * HC + 4 * lane);
        float p = gat_score(ea, wreg, xlv, xrv, attv);
        float mx = p;
        float denom = 1.f;
        float4 acc = xlv;

        // ---- edges, unrolled x2 for latency hiding ----
        int j = s0;
        for (; j + 1 < e0; j += 2) {
            int sa = __builtin_amdgcn_readfirstlane(csr_src[j]);
            int sb = __builtin_amdgcn_readfirstlane(csr_src[j + 1]);
            int ia = __builtin_amdgcn_readfirstlane(csr_eid[j]);
            int ib = __builtin_amdgcn_readfirstlane(csr_eid[j + 1]);
            float eaA[32], eaB[32];
            load_ea(ef + (size_t)ia * EDIM, eaA);
            load_ea(ef + (size_t)ib * EDIM, eaB);
            float4 xla = *(const float4*)(xl + (size_t)sa * HC + 4 * lane);
            float4 xlb = *(const float4*)(xl + (size_t)sb * HC + 4 * lane);
            float pa = gat_score(eaA, wreg, xla, xrv, attv);
            float pb = gat_score(eaB, wreg, xlb, xrv, attv);
            float nm = fmaxf(mx, pa);
            float sc = __expf(mx - nm);
            float aa = __expf(pa - nm);
            denom = denom * sc + aa;
            acc.x = acc.x * sc + xla.x * aa; acc.y = acc.y * sc + xla.y * aa;
            acc.z = acc.z * sc + xla.z * aa; acc.w = acc.w * sc + xla.w * aa;
            mx = nm;
            nm = fmaxf(mx, pb);
            sc = __expf(mx - nm);
            aa = __expf(pb - nm);
            denom = denom * sc + aa;
            acc.x = acc.x * sc + xlb.x * aa; acc.y = acc.y * sc + xlb.y * aa;
            acc.z = acc.z * sc + xlb.z * aa; acc.w = acc.w * sc + xlb.w * aa;
            mx = nm;
        }
        if (j < e0) {
            int sa = __builtin_amdgcn_readfirstlane(csr_src[j]);
            int ia = __builtin_amdgcn_readfirstlane(csr_eid[j]);
            float eaA[32];
            load_ea(ef + (size_t)ia * EDIM, eaA);
            float4 xla = *(const float4*)(xl + (size_t)sa * HC + 4 * lane);
            float pa = gat_score(eaA, wreg, xla, xrv, attv);
            float nm = fmaxf(mx, pa);
            float sc = __expf(mx - nm);
            float aa = __expf(pa - nm);
            denom = denom * sc + aa;
            acc.x = acc.x * sc + xla.x * aa; acc.y = acc.y * sc + xla.y * aa;
            acc.z = acc.z * sc + xla.z * aa; acc.w = acc.w * sc + xla.w * aa;
            mx = nm;
        }

        float inv = 1.f / denom;
        float4 r = make_float4(acc.x * inv + bb.x, acc.y * inv + bb.y,
                               acc.z * inv + bb.z, acc.w * inv + bb.w);
        if (do_relu) {
            r.x = fmaxf(r.x, 0.f); r.y = fmaxf(r.y, 0.f);
            r.z = fmaxf(r.z, 0.f); r.w = fmaxf(r.w, 0.f);
        }
        *(float4*)(out + (size_t)n * HC + 4 * lane) = r;
    }
}

// ---------------------------------------------------------------------------
// In-place LayerNorm over rows of width 64 (one wave per row)
// ---------------------------------------------------------------------------
__global__ void ln_rows(float* __restrict__ y, const float* __restrict__ g,
                        const float* __restrict__ b, int M) {
    int lane = threadIdx.x & 63;
    int wv = threadIdx.x >> 6;
    int n = blockIdx.x * 4 + wv;
    if (n >= M) return;
    float v = y[(size_t)n * 64 + lane];
    float s = v;
    #pragma unroll
    for (int o = 32; o >= 1; o >>= 1) s += __shfl_xor(s, o);
    float mu = s * (1.f / 64.f);
    float dv = v - mu;
    float q = dv * dv;
    #pragma unroll
    for (int o = 32; o >= 1; o >>= 1) q += __shfl_xor(q, o);
    float var = q * (1.f / 64.f);
    y[(size_t)n * 64 + lane] = dv * rsqrtf(var + LN_EPS) * g[lane] + b[lane];
}

// ---------------------------------------------------------------------------
// Graph mean pre-reduction exploiting sorted batch
// ---------------------------------------------------------------------------
__global__ void graph_sum(const float* __restrict__ x, const int* __restrict__ batch,
                          float* __restrict__ gsum, float* __restrict__ gcnt) {
    int c = threadIdx.x;
    int r0 = blockIdx.x * 256;
    int r1 = min(r0 + 256, NN);
    float acc = 0.f;
    int gcur = batch[r0];
    for (int n = r0; n < r1; n++) {
        int g = batch[n];
        if (g != gcur) {
            atomicAdd(&gsum[(size_t)gcur * HC + c], acc);
            acc = 0.f; gcur = g;
        }
        acc += x[(size_t)n * HC + c];
    }
    atomicAdd(&gsum[(size_t)gcur * HC + c], acc);
    if (c == 0) {
        int cnt = 0; gcur = batch[r0];
        for (int n = r0; n < r1; n++) {
            int g = batch[n];
            if (g != gcur) {
                atomicAdd(&gcnt[gcur], (float)cnt);
                cnt = 0; gcur = g;
            }
            cnt++;
        }
        atomicAdd(&gcnt[gcur], (float)cnt);
    }
}

__global__ void glob_kernel(const float* __restrict__ gsum, const float* __restrict__ gcnt,
                            const float* __restrict__ W, const float* __restrict__ bias,
                            const float* __restrict__ g, const float* __restrict__ b,
                            float* __restrict__ out) {
    int gi = blockIdx.x;
    int lane = threadIdx.x;
    float inv = 1.f / fmaxf(gcnt[gi], 1.f);
    float acc = 0.f;
    for (int k = 0; k < HC; k++)
        acc += (gsum[(size_t)gi * HC + k] * inv) * W[(size_t)k * ND + lane];
    acc += bias[lane];
    float s = acc;
    #pragma unroll
    for (int o = 32; o >= 1; o >>= 1) s += __shfl_xor(s, o);
    float mu = s * (1.f / 64.f);
    float dv = acc - mu;
    float q = dv * dv;
    #pragma unroll
    for (int o = 32; o >= 1; o >>= 1) q += __shfl_xor(q, o);
    float var = q * (1.f / 64.f);
    out[(size_t)gi * ND + lane] = dv * rsqrtf(var + LN_EPS) * g[lane] + b[lane];
}

// ---------------------------------------------------------------------------
extern "C" void kernel_launch(void* const* d_in, const int* in_sizes, int n_in,
                              void* d_out, int out_size, void* d_ws, size_t ws_size,
                              hipStream_t stream) {
    (void)in_sizes; (void)n_in; (void)out_size; (void)ws_size;
    const float* node_feature = (const float*)d_in[0];
    const int*   edge_index   = (const int*)d_in[1];
    const float* edge_feature = (const float*)d_in[2];
    const int*   batch        = (const int*)d_in[3];
    const float* Wl0   = (const float*)d_in[4];
    const float* bl0   = (const float*)d_in[5];
    const float* Wr0   = (const float*)d_in[6];
    const float* br0   = (const float*)d_in[7];
    const float* We0   = (const float*)d_in[8];
    const float* att0  = (const float*)d_in[9];
    const float* bias0 = (const float*)d_in[10];
    const float* Wl1   = (const float*)d_in[11];
    const float* bl1   = (const float*)d_in[12];
    const float* Wr1   = (const float*)d_in[13];
    const float* br1   = (const float*)d_in[14];
    const float* We1   = (const float*)d_in[15];
    const float* att1  = (const float*)d_in[16];
    const float* bias1 = (const float*)d_in[17];
    const float* node_W  = (const float*)d_in[18];
    const float* node_b  = (const float*)d_in[19];
    const float* graph_W = (const float*)d_in[20];
    const float* graph_b = (const float*)d_in[21];
    const float* nn_g = (const float*)d_in[22];
    const float* nn_b = (const float*)d_in[23];
    const float* gn_g = (const float*)d_in[24];
    const float* gn_b = (const float*)d_in[25];

    const int* src = edge_index;
    const int* dst = edge_index + NE;

    char* p = (char*)d_ws;
    auto carve = [&](size_t bytes) {
        char* r = p;
        p += (bytes + 255) & ~(size_t)255;
        return r;
    };
    int*   row_ptr   = (int*)carve((NN + 1) * sizeof(int));
    int*   cursor    = (int*)carve(NN * sizeof(int));
    int*   csr_src   = (int*)carve((size_t)NE * sizeof(int));
    int*   csr_eid   = (int*)carve((size_t)NE * sizeof(int));
    float* loop_attr = (float*)carve((size_t)NN * EDIM * sizeof(float));
    float* xl        = (float*)carve((size_t)NN * HC * sizeof(float));
    float* xr        = (float*)carve((size_t)NN * HC * sizeof(float));
    float* xb        = (float*)carve((size_t)NN * HC * sizeof(float));
    float* gsum      = (float*)carve((size_t)(NGG * HC + NGG) * sizeof(float));
    float* gcnt     = gsum + (size_t)NGG * HC;
    // bf16 transposed weight buffers (hi/lo)
    unsigned short* wl0h = (unsigned short*)carve((size_t)DIN * HC * 2 * 2);
    unsigned short* wl0l = wl0h + (size_t)DIN * HC;
    unsigned short* wr0h = (unsigned short*)carve((size_t)DIN * HC * 2 * 2);
    unsigned short* wr0l = wr0h + (size_t)DIN * HC;
    unsigned short* wl1h = (unsigned short*)carve((size_t)HC * HC * 2 * 2);
    unsigned short* wl1l = wl1h + (size_t)HC * HC;
    unsigned short* wr1h = (unsigned short*)carve((size_t)HC * HC * 2 * 2);
    unsigned short* wr1l = wr1h + (size_t)HC * HC;
    unsigned short* nwh  = (unsigned short*)carve((size_t)HC * ND * 2 * 2);
    unsigned short* nwl  = nwh + (size_t)HC * ND;

    hipMemsetAsync(cursor, 0, NN * sizeof(int), stream);
    hipMemsetAsync(gsum, 0, (NGG * HC + NGG) * sizeof(float), stream);

    // CSR + loop_attr + weight conversion (layer-independent)
    count_deg<<<(NE + 255) / 256, 256, 0, stream>>>(dst, cursor);
    scan_deg<<<1, 1024, 0, stream>>>(cursor, row_ptr);
    fill_csr<<<(NE + 255) / 256, 256, 0, stream>>>(src, dst, cursor, csr_src, csr_eid);
    loop_attr_kernel<<<(NN * EDIM + 255) / 256, 256, 0, stream>>>(edge_feature, row_ptr, csr_eid, loop_attr);
    conv_wt<<<(DIN * HC + 255) / 256, 256, 0, stream>>>(Wl0, wl0h, wl0l, DIN, HC);
    conv_wt<<<(DIN * HC + 255) / 256, 256, 0, stream>>>(Wr0, wr0h, wr0l, DIN, HC);
    conv_wt<<<(HC * HC + 255) / 256, 256, 0, stream>>>(Wl1, wl1h, wl1l, HC, HC);
    conv_wt<<<(HC * HC + 255) / 256, 256, 0, stream>>>(Wr1, wr1h, wr1l, HC, HC);
    conv_wt<<<(HC * ND + 255) / 256, 256, 0, stream>>>(node_W, nwh, nwl, HC, ND);

    dim3 g256(HC / 64, (NN + 63) / 64);
    dim3 g64(ND / 64, (NN + 63) / 64);
    // Layer 0
    gemm_mfma<<<g256, 256, 0, stream>>>(node_feature, wl0h, wl0l, bl0, xl, NN, DIN, HC);
    gemm_mfma<<<g256, 256, 0, stream>>>(node_feature, wr0h, wr0l, br0, xr, NN, DIN, HC);
    gat_fused<<<2048, 256, 0, stream>>>(xl, xr, edge_feature, loop_attr, row_ptr, csr_src, csr_eid,
                                        We0, att0, bias0, xb, 1);
    // Layer 1
    gemm_mfma<<<g256, 256, 0, stream>>>(xb, wl1h, wl1l, bl1, xl, NN, HC, HC);
    gemm_mfma<<<g256, 256, 0, stream>>>(xb, wr1h, wr1l, br1, xr, NN, HC, HC);
    gat_fused<<<2048, 256, 0, stream>>>(xl, xr, edge_feature, loop_attr, row_ptr, csr_src, csr_eid,
                                        We1, att1, bias1, xb, 0);

    // Heads
    float* out_local = (float*)d_out;
    float* out_glob  = out_local + (size_t)NN * ND;
    gemm_mfma<<<g64, 256, 0, stream>>>(xb, nwh, nwl, node_b, out_local, NN, HC, ND);
    ln_rows<<<(NN + 3) / 4, 256, 0, stream>>>(out_local, nn_g, nn_b, NN);
    graph_sum<<<(NN + 255) / 256, 256, 0, stream>>>(xb, batch, gsum, gcnt);
    glob_kernel<<<NGG, 64, 0, stream>>>(gsum, gcnt, graph_W, graph_b, gn_g, gn_b, out_glob);
}